// Round 12
// baseline (585.430 us; speedup 1.0000x reference)
//
#include <hip/hip_runtime.h>
#include <hip/hip_bf16.h>
#include <math.h>

#define D_FEAT 128
#define NLAYER 3
#define BN_EPS 1e-5f
#define INV_SQRT_C 0.17677669529663687f  // 1/sqrt(32)
#define SORT_NPB 1024                    // nodes per sort block
#define NREP 8                           // stats replicas (atomic decontention)
#define TP 136                           // gemm LDS tile pitch (shorts)

typedef __bf16 bf16x8 __attribute__((ext_vector_type(8)));
typedef float f32x4 __attribute__((ext_vector_type(4)));

static __device__ __forceinline__ unsigned short f2bf(float f) {
    return __builtin_bit_cast(unsigned short, __float2bfloat16(f));
}
static __device__ __forceinline__ float bfl(unsigned u) { return __uint_as_float(u << 16); }
static __device__ __forceinline__ float bfh(unsigned u) { return __uint_as_float(u & 0xffff0000u); }
static __device__ __forceinline__ unsigned packbf(float a, float b) {
    return (unsigned)f2bf(a) | ((unsigned)f2bf(b) << 16);
}

// ---------------- fused prep: x->bf16 cvt + weight transp/cvt + degree histogram ----------------
// blocks [0,1792): cvt; [1792,2048): weights; [2048,...): hist. deg pre-zeroed.

__global__ void prep_kernel(const float* __restrict__ x, unsigned short* __restrict__ xb,
                            size_t n4,
                            const float* __restrict__ Wq, const float* __restrict__ Wk,
                            const float* __restrict__ Wv, const float* __restrict__ Ws,
                            const float* __restrict__ Wo,
                            unsigned short* __restrict__ Wt, unsigned short* __restrict__ Wot,
                            const int* __restrict__ edst, int E, int* __restrict__ deg)
{
    const int CVTB = 1792;
    const int WEND = 2048;
    int b = blockIdx.x;
    if (b < CVTB) {
        for (size_t t = (size_t)b * blockDim.x + threadIdx.x; t < n4;
             t += (size_t)CVTB * blockDim.x) {
            size_t i = t * 4;
            float4 v = *(const float4*)(x + i);
            ushort4 u;
            u.x = f2bf(v.x); u.y = f2bf(v.y); u.z = f2bf(v.z); u.w = f2bf(v.w);
            *(ushort4*)(xb + i) = u;
        }
    } else if (b < WEND) {
        const int permat = 16384;
        const int main_total = NLAYER * 4 * permat;
        const int total = main_total + 64 * 128;
        const int WB = WEND - CVTB;
        for (int i = (b - CVTB) * blockDim.x + threadIdx.x; i < total;
             i += WB * blockDim.x) {
            if (i < main_total) {
                int l = i / (4 * permat);
                int rem = i - l * (4 * permat);
                int mat = rem / permat;
                int e = rem - mat * permat;
                int nn = e >> 7;
                int kk = e & 127;
                const float* src = (mat == 0) ? Wq : (mat == 1) ? Wk : (mat == 2) ? Wv : Ws;
                Wt[(size_t)l * 4 * permat + mat * permat + nn * 128 + kk] =
                    f2bf(src[(size_t)l * permat + kk * 128 + nn]);
            } else {
                int e = i - main_total;
                int nn = e >> 7;
                int kk = e & 127;
                Wot[nn * 128 + kk] = f2bf(Wo[kk * 64 + nn]);
            }
        }
    } else {
        int e = (b - WEND) * blockDim.x + threadIdx.x;
        if (e < E) atomicAdd(&deg[edst[e]], 1);
    }
}

// ---------------- CSR build ----------------

__global__ __launch_bounds__(256) void scan1_kernel(const int* __restrict__ deg, int n,
                                                    int* __restrict__ rowptr,
                                                    int* __restrict__ partials) {
    int b = blockIdx.x, tid = threadIdx.x;
    int base = b * 1024 + tid * 4;
    int4 d = {0, 0, 0, 0};
    if (base + 3 < n) d = *(const int4*)(deg + base);
    else {
        if (base + 0 < n) d.x = deg[base + 0];
        if (base + 1 < n) d.y = deg[base + 1];
        if (base + 2 < n) d.z = deg[base + 2];
        if (base + 3 < n) d.w = deg[base + 3];
    }
    int p0 = d.x, p1 = p0 + d.y, p2 = p1 + d.z, p3 = p2 + d.w;
    int v = p3;
    int lane = tid & 63;
    #pragma unroll
    for (int off = 1; off < 64; off <<= 1) {
        int t = __shfl_up(v, off);
        if (lane >= off) v += t;
    }
    __shared__ int wsum[4];
    int w = tid >> 6;
    if (lane == 63) wsum[w] = v;
    __syncthreads();
    int woff = 0;
    #pragma unroll
    for (int j = 0; j < 4; ++j) if (j < w) woff += wsum[j];
    int excl = woff + v - p3;
    if (base + 0 < n) rowptr[base + 1] = excl + p0;
    if (base + 1 < n) rowptr[base + 2] = excl + p1;
    if (base + 2 < n) rowptr[base + 3] = excl + p2;
    if (base + 3 < n) rowptr[base + 4] = excl + p3;
    if (tid == 255) partials[b] = excl + p3;
    if (b == 0 && tid == 0) rowptr[0] = 0;
}

__global__ void scan2_kernel(int* __restrict__ partials, int nb) {
    int lane = threadIdx.x;
    int v = (lane < nb) ? partials[lane] : 0;
    #pragma unroll
    for (int off = 1; off < 64; off <<= 1) {
        int t = __shfl_up(v, off);
        if (lane >= off) v += t;
    }
    if (lane < nb) partials[lane] = v;  // inclusive
}

// Fused: finalize rowptr (add block offset) AND per-block degree histogram (descending).
__global__ __launch_bounds__(256) void scan3_hist_kernel(
    int* __restrict__ rowptr, int n, const int* __restrict__ partials,
    int B, int* __restrict__ bhist)
{
    __shared__ int h[256];
    __shared__ int oldv[SORT_NPB];
    int b = blockIdx.x, tid = threadIdx.x;
    h[tid] = 0;
    int off = (b == 0) ? 0 : partials[b - 1];
    #pragma unroll
    for (int j = 0; j < SORT_NPB / 256; ++j) {
        int loc = j * 256 + tid;
        int i = b * SORT_NPB + loc;
        oldv[loc] = (i < n) ? rowptr[i + 1] : 0;
    }
    __syncthreads();
    #pragma unroll
    for (int j = 0; j < SORT_NPB / 256; ++j) {
        int loc = j * 256 + tid;
        int i = b * SORT_NPB + loc;
        if (i < n) {
            int d = (loc == 0) ? oldv[0] : (oldv[loc] - oldv[loc - 1]);
            if (d > 255) d = 255;
            atomicAdd(&h[255 - d], 1);        // descending
            rowptr[i + 1] = oldv[loc] + off;  // finalize
        }
    }
    __syncthreads();
    bhist[tid * B + b] = h[tid];
}

__global__ void scatter_kernel(const int* __restrict__ src, const int* __restrict__ dst, int E,
                               const int* __restrict__ rowptr, int* __restrict__ cursor,
                               int* __restrict__ csrsrc) {
    int e = blockIdx.x * blockDim.x + threadIdx.x;
    if (e < E) {
        int d = dst[e];
        int p = atomicAdd(&cursor[d], 1);
        csrsrc[rowptr[d] + p] = src[e];
    }
}

__global__ __launch_bounds__(256) void bin_colscan_kernel(
    int* __restrict__ bhist, int B, int* __restrict__ binoff)
{
    int d = threadIdx.x;
    int run = 0;
    for (int b = 0; b < B; ++b) {
        int c = bhist[d * B + b];
        bhist[d * B + b] = run;
        run += c;
    }
    __shared__ int sd[256];
    sd[d] = run;
    __syncthreads();
    int v = run;
    for (int s = 1; s < 256; s <<= 1) {
        int t = (d >= s) ? sd[d - s] : 0;
        __syncthreads();
        sd[d] += t;
        __syncthreads();
    }
    binoff[d] = sd[d] - v;  // exclusive
}

__global__ __launch_bounds__(256) void bin_order_kernel(
    const int* __restrict__ rowptr, int n, int B,
    const int* __restrict__ bhist, const int* __restrict__ binoff,
    int* __restrict__ order)
{
    __shared__ int cur[256];
    int b = blockIdx.x, tid = threadIdx.x;
    cur[tid] = binoff[tid] + bhist[tid * B + b];
    __syncthreads();
    #pragma unroll
    for (int j = 0; j < SORT_NPB / 256; ++j) {
        int i = b * SORT_NPB + j * 256 + tid;
        if (i < n) {
            int d = rowptr[i + 1] - rowptr[i];
            if (d > 255) d = 255;
            int pos = atomicAdd(&cur[255 - d], 1);
            order[pos] = i;
        }
    }
}

// ---------------- LDS-free direct-register MFMA GEMM, ct-pairs, inline BN,
// LDS-transposed coalesced epilogue ----------------

__global__ __launch_bounds__(256, 2) void gemm_qkvs_kernel(
    const unsigned short* __restrict__ A,
    const float* __restrict__ stats, const float* __restrict__ g,
    const float* __restrict__ bb, int mode, int M,
    const unsigned short* __restrict__ Wt,
    const float* __restrict__ b0, const float* __restrict__ b1,
    const float* __restrict__ b2, const float* __restrict__ b3,
    unsigned short* __restrict__ q, unsigned short* __restrict__ kv,
    unsigned short* __restrict__ s)
{
    __shared__ float scale[128], shift[128];
    __shared__ unsigned short tile[128 * TP];
    int r0 = blockIdx.x * 128;
    int tid = threadIdx.x;
    int wid = tid >> 6, lane = tid & 63;
    int wm = wid >> 1, wn = wid & 1;
    int lr = lane & 15, lk = lane >> 4;

    if (mode && tid < 128) {
        float ssum = 0.f, qsum = 0.f;
        #pragma unroll
        for (int r = 0; r < NREP; ++r) {
            ssum += stats[r * 1024 + tid];
            qsum += stats[r * 1024 + 512 + tid];
        }
        float invN = 1.0f / (float)M;
        float mu = ssum * invN;
        float var = qsum * invN - mu * mu;
        float sc = rsqrtf(var + BN_EPS) * g[tid];
        scale[tid] = sc;
        shift[tid] = bb[tid] - mu * sc;
    }
    __syncthreads();

    bf16x8 a[4][4];
    #pragma unroll
    for (int ks = 0; ks < 4; ++ks) {
        int ko = ks * 32 + lk * 8;
        #pragma unroll
        for (int mi = 0; mi < 4; ++mi) {
            int arow = r0 + wm * 64 + mi * 16 + lr;
            int4 t = {0, 0, 0, 0};
            if (arow < M) t = *(const int4*)(A + (size_t)arow * 128 + ko);
            if (mode) {
                float4 sc0 = *(const float4*)&scale[ko];
                float4 sc1 = *(const float4*)&scale[ko + 4];
                float4 sh0 = *(const float4*)&shift[ko];
                float4 sh1 = *(const float4*)&shift[ko + 4];
                float v0 = fmaxf(bfl(t.x) * sc0.x + sh0.x, 0.f);
                float v1 = fmaxf(bfh(t.x) * sc0.y + sh0.y, 0.f);
                float v2 = fmaxf(bfl(t.y) * sc0.z + sh0.z, 0.f);
                float v3 = fmaxf(bfh(t.y) * sc0.w + sh0.w, 0.f);
                float v4 = fmaxf(bfl(t.z) * sc1.x + sh1.x, 0.f);
                float v5 = fmaxf(bfh(t.z) * sc1.y + sh1.y, 0.f);
                float v6 = fmaxf(bfl(t.w) * sc1.z + sh1.z, 0.f);
                float v7 = fmaxf(bfh(t.w) * sc1.w + sh1.w, 0.f);
                t.x = (int)packbf(v0, v1); t.y = (int)packbf(v2, v3);
                t.z = (int)packbf(v4, v5); t.w = (int)packbf(v6, v7);
            }
            a[mi][ks] = __builtin_bit_cast(bf16x8, t);
        }
    }

    #pragma unroll
    for (int cc = 0; cc < 2; ++cc) {
        int ct = blockIdx.y * 2 + cc;
        const unsigned short* W = Wt + (size_t)ct * 16384;

        f32x4 acc[4][4] = {};
        #pragma unroll
        for (int ks = 0; ks < 4; ++ks) {
            int ko = ks * 32 + lk * 8;
            bf16x8 b[4];
            #pragma unroll
            for (int nj = 0; nj < 4; ++nj) {
                int4 t = *(const int4*)(W + (size_t)(wn * 64 + nj * 16 + lr) * 128 + ko);
                b[nj] = __builtin_bit_cast(bf16x8, t);
            }
            #pragma unroll
            for (int mi = 0; mi < 4; ++mi)
                #pragma unroll
                for (int nj = 0; nj < 4; ++nj)
                    acc[mi][nj] = __builtin_amdgcn_mfma_f32_16x16x32_bf16(
                        a[mi][ks], b[nj], acc[mi][nj], 0, 0, 0);
        }

        const float* bias = (ct == 0) ? b0 : (ct == 1) ? b1 : (ct == 2) ? b2 : b3;
        __syncthreads();
        #pragma unroll
        for (int mi = 0; mi < 4; ++mi) {
            #pragma unroll
            for (int nj = 0; nj < 4; ++nj) {
                int col = wn * 64 + nj * 16 + lr;
                float bv = bias[col];
                #pragma unroll
                for (int reg = 0; reg < 4; ++reg) {
                    int rloc = wm * 64 + mi * 16 + lk * 4 + reg;
                    tile[rloc * TP + col] = f2bf(acc[mi][nj][reg] + bv);
                }
            }
        }
        __syncthreads();
        #pragma unroll
        for (int it = 0; it < 8; ++it) {
            int flat = (it * 256 + tid) * 8;
            int row = flat >> 7, col = flat & 127;
            int rw = r0 + row;
            if (rw < M) {
                int4 v = *(const int4*)&tile[row * TP + col];
                if (ct == 0) *(int4*)(q + (size_t)rw * 128 + col) = v;
                else if (ct == 1) *(int4*)(kv + (size_t)rw * 256 + col) = v;
                else if (ct == 2) *(int4*)(kv + (size_t)rw * 256 + 128 + col) = v;
                else *(int4*)(s + (size_t)rw * 128 + col) = v;
            }
        }
    }
}

// Final: out[M x 64] = BNrelu(A) @ Wo + bo (f32), inline BN; accumulates output stats.
__global__ __launch_bounds__(256, 2) void gemm_final_kernel(
    const unsigned short* __restrict__ A,
    const float* __restrict__ stats, const float* __restrict__ g,
    const float* __restrict__ bb, int M,
    const unsigned short* __restrict__ Wot, const float* __restrict__ bias,
    float* __restrict__ out, float* __restrict__ statsOut)
{
    __shared__ float scale[128], shift[128];
    __shared__ float fs[64], fq[64];
    int r0 = blockIdx.x * 128;
    int tid = threadIdx.x;
    int wid = tid >> 6, lane = tid & 63;
    int wm = wid >> 1, wn = wid & 1;
    int lr = lane & 15, lk = lane >> 4;

    if (tid < 128) {
        float ssum = 0.f, qsum = 0.f;
        #pragma unroll
        for (int r = 0; r < NREP; ++r) {
            ssum += stats[r * 1024 + tid];
            qsum += stats[r * 1024 + 512 + tid];
        }
        float invN = 1.0f / (float)M;
        float mu = ssum * invN;
        float var = qsum * invN - mu * mu;
        float sc = rsqrtf(var + BN_EPS) * g[tid];
        scale[tid] = sc;
        shift[tid] = bb[tid] - mu * sc;
    }
    if (tid < 64) { fs[tid] = 0.f; fq[tid] = 0.f; }
    __syncthreads();

    bf16x8 a[4][4];
    #pragma unroll
    for (int ks = 0; ks < 4; ++ks) {
        int ko = ks * 32 + lk * 8;
        #pragma unroll
        for (int mi = 0; mi < 4; ++mi) {
            int arow = r0 + wm * 64 + mi * 16 + lr;
            int4 t = {0, 0, 0, 0};
            if (arow < M) t = *(const int4*)(A + (size_t)arow * 128 + ko);
            float4 sc0 = *(const float4*)&scale[ko];
            float4 sc1 = *(const float4*)&scale[ko + 4];
            float4 sh0 = *(const float4*)&shift[ko];
            float4 sh1 = *(const float4*)&shift[ko + 4];
            float v0 = fmaxf(bfl(t.x) * sc0.x + sh0.x, 0.f);
            float v1 = fmaxf(bfh(t.x) * sc0.y + sh0.y, 0.f);
            float v2 = fmaxf(bfl(t.y) * sc0.z + sh0.z, 0.f);
            float v3 = fmaxf(bfh(t.y) * sc0.w + sh0.w, 0.f);
            float v4 = fmaxf(bfl(t.z) * sc1.x + sh1.x, 0.f);
            float v5 = fmaxf(bfh(t.z) * sc1.y + sh1.y, 0.f);
            float v6 = fmaxf(bfl(t.w) * sc1.z + sh1.z, 0.f);
            float v7 = fmaxf(bfh(t.w) * sc1.w + sh1.w, 0.f);
            t.x = (int)packbf(v0, v1); t.y = (int)packbf(v2, v3);
            t.z = (int)packbf(v4, v5); t.w = (int)packbf(v6, v7);
            a[mi][ks] = __builtin_bit_cast(bf16x8, t);
        }
    }

    f32x4 acc[4][2] = {};
    #pragma unroll
    for (int ks = 0; ks < 4; ++ks) {
        int ko = ks * 32 + lk * 8;
        bf16x8 b[2];
        #pragma unroll
        for (int nj = 0; nj < 2; ++nj) {
            int4 t = *(const int4*)(Wot + (size_t)(wn * 32 + nj * 16 + lr) * 128 + ko);
            b[nj] = __builtin_bit_cast(bf16x8, t);
        }
        #pragma unroll
        for (int mi = 0; mi < 4; ++mi)
            #pragma unroll
            for (int nj = 0; nj < 2; ++nj)
                acc[mi][nj] = __builtin_amdgcn_mfma_f32_16x16x32_bf16(
                    a[mi][ks], b[nj], acc[mi][nj], 0, 0, 0);
    }

    float csum[2] = {0.f, 0.f}, csq[2] = {0.f, 0.f};
    #pragma unroll
    for (int mi = 0; mi < 4; ++mi) {
        #pragma unroll
        for (int nj = 0; nj < 2; ++nj) {
            int col = wn * 32 + nj * 16 + lr;
            float bv = bias[col];
            #pragma unroll
            for (int reg = 0; reg < 4; ++reg) {
                int rw = r0 + wm * 64 + mi * 16 + lk * 4 + reg;
                if (rw < M) {
                    float val = acc[mi][nj][reg] + bv;
                    out[(size_t)rw * 64 + col] = val;
                    csum[nj] += val;
                    csq[nj] += val * val;
                }
            }
        }
    }
    #pragma unroll
    for (int nj = 0; nj < 2; ++nj) {
        csum[nj] += __shfl_xor(csum[nj], 16);
        csum[nj] += __shfl_xor(csum[nj], 32);
        csq[nj]  += __shfl_xor(csq[nj], 16);
        csq[nj]  += __shfl_xor(csq[nj], 32);
    }
    if (lane < 16) {
        #pragma unroll
        for (int nj = 0; nj < 2; ++nj) {
            int col = wn * 32 + nj * 16 + lr;
            atomicAdd(&fs[col], csum[nj]);
            atomicAdd(&fq[col], csq[nj]);
        }
    }
    __syncthreads();
    if (tid < 64) atomicAdd(&statsOut[tid], fs[tid]);
    else if (tid < 128) atomicAdd(&statsOut[512 + tid - 64], fq[tid - 64]);
}

// ---------------- Fused attention: 4 nodes/wave, software-pipelined double-buffer ----------------

#define LOADCHUNK(IO, K_, V_)                                              \
    {                                                                      \
        int io_ = (IO);                                                    \
        _Pragma("unroll")                                                  \
        for (int j = 0; j < 8; ++j) {                                      \
            bool av_ = (io_ + j) < deg;                                    \
            int e_ = csrsrc[r0 + io_ + j];                                 \
            e_ = av_ ? e_ : 0;                                             \
            const unsigned short* row_ = kv + (size_t)e_ * 256 + gl * 8;   \
            K_[j] = *(const int4*)(row_);                                  \
            V_[j] = *(const int4*)(row_ + 128);                            \
        }                                                                  \
    }

#define COMPUTECHUNK(IO, K_, V_)                                           \
    {                                                                      \
        int io_ = (IO);                                                    \
        float sc[8];                                                       \
        _Pragma("unroll")                                                  \
        for (int j = 0; j < 8; ++j) {                                      \
            float p = qf[0] * bfl(K_[j].x) + qf[1] * bfh(K_[j].x)          \
                    + qf[2] * bfl(K_[j].y) + qf[3] * bfh(K_[j].y)          \
                    + qf[4] * bfl(K_[j].z) + qf[5] * bfh(K_[j].z)          \
                    + qf[6] * bfl(K_[j].w) + qf[7] * bfh(K_[j].w);         \
            p += __shfl_xor(p, 1);                                         \
            p += __shfl_xor(p, 2);                                         \
            sc[j] = ((io_ + j) < deg) ? p * INV_SQRT_C : -INFINITY;        \
        }                                                                  \
        float mn = m;                                                      \
        _Pragma("unroll")                                                  \
        for (int j = 0; j < 8; ++j) mn = fmaxf(mn, sc[j]);                 \
        if (mn > m) {                                                      \
            float scl = __expf(m - mn);                                    \
            ssum *= scl;                                                   \
            _Pragma("unroll")                                              \
            for (int c = 0; c < 8; ++c) acc[c] *= scl;                     \
            m = mn;                                                        \
        }                                                                  \
        _Pragma("unroll")                                                  \
        for (int j = 0; j < 8; ++j) {                                      \
            float ej = ((io_ + j) < deg) ? __expf(sc[j] - m) : 0.f;        \
            ssum += ej;                                                    \
            acc[0] += ej * bfl(V_[j].x); acc[1] += ej * bfh(V_[j].x);      \
            acc[2] += ej * bfl(V_[j].y); acc[3] += ej * bfh(V_[j].y);      \
            acc[4] += ej * bfl(V_[j].z); acc[5] += ej * bfh(V_[j].z);      \
            acc[6] += ej * bfl(V_[j].w); acc[7] += ej * bfh(V_[j].w);      \
        }                                                                  \
    }

__global__ __launch_bounds__(256) void attn_kernel(
    const unsigned short* __restrict__ q, const unsigned short* __restrict__ kv,
    const unsigned short* __restrict__ sk,
    const int* __restrict__ rowptr, const int* __restrict__ csrsrc,
    const int* __restrict__ order,
    unsigned short* __restrict__ hnext, float* __restrict__ stats, int N)
{
    __shared__ float ls[128], lq2[128];
    int tid = threadIdx.x;
    if (tid < 128) { ls[tid] = 0.f; lq2[tid] = 0.f; }
    __syncthreads();

    int wave = (blockIdx.x * blockDim.x + tid) >> 6;
    int lane = tid & 63;
    int gl = lane & 15;
    int slot = wave * 4 + (lane >> 4);
    bool nv = slot < N;
    int n = nv ? order[slot] : 0;

    int r0 = rowptr[n], r1 = rowptr[n + 1];
    int deg = nv ? (r1 - r0) : 0;
    int dmax = deg;
    dmax = max(dmax, __shfl_xor(dmax, 16));
    dmax = max(dmax, __shfl_xor(dmax, 32));

    int4 qu = *(const int4*)(q + (size_t)n * 128 + gl * 8);
    float qf[8];
    qf[0] = bfl(qu.x); qf[1] = bfh(qu.x); qf[2] = bfl(qu.y); qf[3] = bfh(qu.y);
    qf[4] = bfl(qu.z); qf[5] = bfh(qu.z); qf[6] = bfl(qu.w); qf[7] = bfh(qu.w);

    float m = -INFINITY, ssum = 0.f;
    float acc[8] = {};

    int4 Ka[8], Va[8], Kb[8], Vb[8];
    if (dmax > 0) {
        LOADCHUNK(0, Ka, Va);
        int i = 0;
        while (true) {
            // chunk i in Ka/Va; prefetch i+8 into Kb/Vb
            if (i + 8 < dmax) LOADCHUNK(i + 8, Kb, Vb);
            COMPUTECHUNK(i, Ka, Va);
            i += 8;
            if (i >= dmax) break;
            if (i + 8 < dmax) LOADCHUNK(i + 8, Ka, Va);
            COMPUTECHUNK(i, Kb, Vb);
            i += 8;
            if (i >= dmax) break;
        }
    }

    float o[8];
    if (nv) {
        float inv = (ssum > 0.f) ? 1.0f / ssum : 0.f;
        int4 su = *(const int4*)(sk + (size_t)n * 128 + gl * 8);
        o[0] = acc[0] * inv + bfl(su.x); o[1] = acc[1] * inv + bfh(su.x);
        o[2] = acc[2] * inv + bfl(su.y); o[3] = acc[3] * inv + bfh(su.y);
        o[4] = acc[4] * inv + bfl(su.z); o[5] = acc[5] * inv + bfh(su.z);
        o[6] = acc[6] * inv + bfl(su.w); o[7] = acc[7] * inv + bfh(su.w);
        int4 st;
        st.x = (int)packbf(o[0], o[1]); st.y = (int)packbf(o[2], o[3]);
        st.z = (int)packbf(o[4], o[5]); st.w = (int)packbf(o[6], o[7]);
        *(int4*)(hnext + (size_t)n * 128 + gl * 8) = st;
    } else {
        #pragma unroll
        for (int c = 0; c < 8; ++c) o[c] = 0.f;
    }

    // fused BN stats: wave reduce -> LDS -> one replica of global stats
    float s8[8], q8[8];
    #pragma unroll
    for (int c = 0; c < 8; ++c) { s8[c] = o[c]; q8[c] = o[c] * o[c]; }
    #pragma unroll
    for (int c = 0; c < 8; ++c) {
        s8[c] += __shfl_xor(s8[c], 16); s8[c] += __shfl_xor(s8[c], 32);
        q8[c] += __shfl_xor(q8[c], 16); q8[c] += __shfl_xor(q8[c], 32);
    }
    if (lane < 16) {
        #pragma unroll
        for (int c = 0; c < 8; ++c) {
            atomicAdd(&ls[gl * 8 + c], s8[c]);
            atomicAdd(&lq2[gl * 8 + c], q8[c]);
        }
    }
    __syncthreads();
    float* srep = stats + (blockIdx.x & (NREP - 1)) * 1024;
    if (tid < 128) atomicAdd(&srep[tid], ls[tid]);
    else atomicAdd(&srep[512 + tid - 128], lq2[tid - 128]);
}

// ---------------- final BN apply ----------------

__global__ __launch_bounds__(256) void bn_apply_f32_kernel(
    const float* __restrict__ x, float* __restrict__ y,
    const float* __restrict__ stats, const float* __restrict__ g,
    const float* __restrict__ b, int N, int F)
{
    __shared__ float scale[128], shift[128];
    int tid = threadIdx.x;
    if (tid < F) {
        float invN = 1.0f / (float)N;
        float mu = stats[tid] * invN;
        float var = stats[512 + tid] * invN - mu * mu;
        float sc = rsqrtf(var + BN_EPS) * g[tid];
        scale[tid] = sc;
        shift[tid] = b[tid] - mu * sc;
    }
    __syncthreads();
    size_t total4 = (size_t)N * F >> 2;
    int Fm = F - 1;
    for (size_t t = (size_t)blockIdx.x * blockDim.x + tid; t < total4;
         t += (size_t)gridDim.x * blockDim.x) {
        size_t i = t * 4;
        int f = (int)(i & (size_t)Fm);
        float4 v = *(const float4*)(x + i);
        float4 o;
        o.x = fmaxf(v.x * scale[f + 0] + shift[f + 0], 0.f);
        o.y = fmaxf(v.y * scale[f + 1] + shift[f + 1], 0.f);
        o.z = fmaxf(v.z * scale[f + 2] + shift[f + 2], 0.f);
        o.w = fmaxf(v.w * scale[f + 3] + shift[f + 3], 0.f);
        *(float4*)(y + i) = o;
    }
}

// ---------------- launch ----------------

static inline size_t al16(size_t x) { return (x + 15) & ~(size_t)15; }

extern "C" void kernel_launch(void* const* d_in, const int* in_sizes, int n_in,
                              void* d_out, int out_size, void* d_ws, size_t ws_size,
                              hipStream_t stream) {
    const float* x    = (const float*)d_in[0];
    const int*   edge = (const int*)d_in[1];
    const float* Wq   = (const float*)d_in[2];
    const float* bq   = (const float*)d_in[3];
    const float* Wk   = (const float*)d_in[4];
    const float* bk   = (const float*)d_in[5];
    const float* Wv   = (const float*)d_in[6];
    const float* bv   = (const float*)d_in[7];
    const float* Wsk  = (const float*)d_in[8];
    const float* bsk  = (const float*)d_in[9];
    const float* bng  = (const float*)d_in[10];
    const float* bnb  = (const float*)d_in[11];
    const float* Wo   = (const float*)d_in[12];
    const float* bo   = (const float*)d_in[13];
    const float* bnog = (const float*)d_in[14];
    const float* bnob = (const float*)d_in[15];

    const int N = in_sizes[0] / D_FEAT;
    const int E = in_sizes[1] / 2;
    const int* esrc = edge;
    const int* edst = edge + E;

    const int SB = (N + SORT_NPB - 1) / SORT_NPB;
    const size_t STATS_F = (size_t)(NLAYER * NREP + 1) * 1024;

    char* wsb = (char*)d_ws;
    unsigned short* xb = (unsigned short*)wsb; wsb += al16((size_t)N * 128 * 2);
    unsigned short* kv = (unsigned short*)wsb; wsb += al16((size_t)N * 256 * 2);
    unsigned short* q  = (unsigned short*)wsb; wsb += al16((size_t)N * 128 * 2);
    unsigned short* s  = (unsigned short*)wsb; wsb += al16((size_t)N * 128 * 2);
    unsigned short* hnext = (unsigned short*)wsb; wsb += al16((size_t)N * 128 * 2);
    float* outpre = (float*)wsb; wsb += al16((size_t)N * 64 * 4);
    unsigned short* Wt  = (unsigned short*)wsb; wsb += al16((size_t)NLAYER * 4 * 16384 * 2);
    unsigned short* Wot = (unsigned short*)wsb; wsb += al16((size_t)64 * 128 * 2);
    // zero-region: stats | deg | cursor (one memset)
    float* stats  = (float*)wsb; wsb += al16(STATS_F * 4);
    int* deg      = (int*)wsb;   wsb += al16((size_t)N * 4);
    int* cursor   = (int*)wsb;   wsb += al16((size_t)N * 4);
    size_t zero_bytes = (char*)wsb - (char*)stats;
    int* rowptr   = (int*)wsb;   wsb += al16((size_t)(N + 1) * 4);
    int* csrsrc   = (int*)wsb;   wsb += al16((size_t)(E + 64) * 4);  // +pad for chunk overread
    int* partials = (int*)wsb;   wsb += al16(256 * 4);
    int* bhist    = (int*)wsb;   wsb += al16((size_t)256 * SB * 4);
    int* binoff   = (int*)wsb;   wsb += al16(256 * 4);
    int* order    = (int*)wsb;   wsb += al16((size_t)N * 4);

    hipMemsetAsync(stats, 0, zero_bytes, stream);
    const int prep_blocks = 2048 + (E + 255) / 256;
    prep_kernel<<<prep_blocks, 256, 0, stream>>>(x, xb, (size_t)N * 128 / 4,
                                                 Wq, Wk, Wv, Wsk, Wo, Wt, Wot,
                                                 edst, E, deg);

    // CSR build + degree sort
    const int nb1 = (N + 1023) / 1024;
    scan1_kernel<<<nb1, 256, 0, stream>>>(deg, N, rowptr, partials);
    scan2_kernel<<<1, 64, 0, stream>>>(partials, nb1);
    scan3_hist_kernel<<<SB, 256, 0, stream>>>(rowptr, N, partials, SB, bhist);
    scatter_kernel<<<(E + 255) / 256, 256, 0, stream>>>(esrc, edst, E, rowptr, cursor, csrsrc);
    bin_colscan_kernel<<<1, 256, 0, stream>>>(bhist, SB, binoff);
    bin_order_kernel<<<SB, 256, 0, stream>>>(rowptr, N, SB, bhist, binoff, order);

    const int gemm_rb = (N + 127) / 128;
    const int attn_blocks = (N + 15) / 16;
    const unsigned short* hin = xb;
    for (int l = 0; l < NLAYER; ++l) {
        const float* statsIn = (l == 0) ? (const float*)nullptr
                                        : stats + (size_t)(l - 1) * NREP * 1024;
        const float* gIn = (l == 0) ? (const float*)nullptr : bng + (l - 1) * 128;
        const float* bIn = (l == 0) ? (const float*)nullptr : bnb + (l - 1) * 128;
        gemm_qkvs_kernel<<<dim3(gemm_rb, 2), 256, 0, stream>>>(
            hin, statsIn, gIn, bIn, (l == 0) ? 0 : 1, N,
            Wt + (size_t)l * 4 * 16384,
            bq + l * 128, bk + l * 128, bv + l * 128, bsk + l * 128,
            q, kv, s);
        attn_kernel<<<attn_blocks, 256, 0, stream>>>(q, kv, s, rowptr, csrsrc, order,
                                                     hnext, stats + (size_t)l * NREP * 1024, N);
        hin = hnext;
    }

    float* fstats = stats + (size_t)NLAYER * NREP * 1024;
    gemm_final_kernel<<<gemm_rb, 256, 0, stream>>>(
        hnext, stats + (size_t)2 * NREP * 1024, bng + 2 * 128, bnb + 2 * 128, N,
        Wot, bo, outpre, fstats);
    bn_apply_f32_kernel<<<2048, 256, 0, stream>>>(outpre, (float*)d_out, fstats,
                                                  bnog, bnob, N, 64);
}

// Round 13
// 442.733 us; speedup vs baseline: 1.3223x; 1.3223x over previous
//
#include <hip/hip_runtime.h>
#include <hip/hip_bf16.h>
#include <math.h>

#define D_FEAT 128
#define NLAYER 3
#define BN_EPS 1e-5f
#define INV_SQRT_C 0.17677669529663687f  // 1/sqrt(32)
#define SORT_NPB 1024                    // nodes per sort block
#define NREP 8                           // stats replicas (atomic decontention)
#define TP 136                           // gemm LDS tile pitch (shorts)

typedef __bf16 bf16x8 __attribute__((ext_vector_type(8)));
typedef float f32x4 __attribute__((ext_vector_type(4)));

static __device__ __forceinline__ unsigned short f2bf(float f) {
    return __builtin_bit_cast(unsigned short, __float2bfloat16(f));
}
static __device__ __forceinline__ float bfl(unsigned u) { return __uint_as_float(u << 16); }
static __device__ __forceinline__ float bfh(unsigned u) { return __uint_as_float(u & 0xffff0000u); }
static __device__ __forceinline__ unsigned packbf(float a, float b) {
    return (unsigned)f2bf(a) | ((unsigned)f2bf(b) << 16);
}

// ---------------- fused prep: x->bf16 cvt + weight transp/cvt + degree histogram ----------------
// blocks [0,1792): cvt; [1792,2048): weights; [2048,...): hist. deg pre-zeroed.

__global__ void prep_kernel(const float* __restrict__ x, unsigned short* __restrict__ xb,
                            size_t n4,
                            const float* __restrict__ Wq, const float* __restrict__ Wk,
                            const float* __restrict__ Wv, const float* __restrict__ Ws,
                            const float* __restrict__ Wo,
                            unsigned short* __restrict__ Wt, unsigned short* __restrict__ Wot,
                            const int* __restrict__ edst, int E, int* __restrict__ deg)
{
    const int CVTB = 1792;
    const int WEND = 2048;
    int b = blockIdx.x;
    if (b < CVTB) {
        for (size_t t = (size_t)b * blockDim.x + threadIdx.x; t < n4;
             t += (size_t)CVTB * blockDim.x) {
            size_t i = t * 4;
            float4 v = *(const float4*)(x + i);
            ushort4 u;
            u.x = f2bf(v.x); u.y = f2bf(v.y); u.z = f2bf(v.z); u.w = f2bf(v.w);
            *(ushort4*)(xb + i) = u;
        }
    } else if (b < WEND) {
        const int permat = 16384;
        const int main_total = NLAYER * 4 * permat;
        const int total = main_total + 64 * 128;
        const int WB = WEND - CVTB;
        for (int i = (b - CVTB) * blockDim.x + threadIdx.x; i < total;
             i += WB * blockDim.x) {
            if (i < main_total) {
                int l = i / (4 * permat);
                int rem = i - l * (4 * permat);
                int mat = rem / permat;
                int e = rem - mat * permat;
                int nn = e >> 7;
                int kk = e & 127;
                const float* src = (mat == 0) ? Wq : (mat == 1) ? Wk : (mat == 2) ? Wv : Ws;
                Wt[(size_t)l * 4 * permat + mat * permat + nn * 128 + kk] =
                    f2bf(src[(size_t)l * permat + kk * 128 + nn]);
            } else {
                int e = i - main_total;
                int nn = e >> 7;
                int kk = e & 127;
                Wot[nn * 128 + kk] = f2bf(Wo[kk * 64 + nn]);
            }
        }
    } else {
        int e = (b - WEND) * blockDim.x + threadIdx.x;
        if (e < E) atomicAdd(&deg[edst[e]], 1);
    }
}

// ---------------- CSR build ----------------

__global__ __launch_bounds__(256) void scan1_kernel(const int* __restrict__ deg, int n,
                                                    int* __restrict__ rowptr,
                                                    int* __restrict__ partials) {
    int b = blockIdx.x, tid = threadIdx.x;
    int base = b * 1024 + tid * 4;
    int4 d = {0, 0, 0, 0};
    if (base + 3 < n) d = *(const int4*)(deg + base);
    else {
        if (base + 0 < n) d.x = deg[base + 0];
        if (base + 1 < n) d.y = deg[base + 1];
        if (base + 2 < n) d.z = deg[base + 2];
        if (base + 3 < n) d.w = deg[base + 3];
    }
    int p0 = d.x, p1 = p0 + d.y, p2 = p1 + d.z, p3 = p2 + d.w;
    int v = p3;
    int lane = tid & 63;
    #pragma unroll
    for (int off = 1; off < 64; off <<= 1) {
        int t = __shfl_up(v, off);
        if (lane >= off) v += t;
    }
    __shared__ int wsum[4];
    int w = tid >> 6;
    if (lane == 63) wsum[w] = v;
    __syncthreads();
    int woff = 0;
    #pragma unroll
    for (int j = 0; j < 4; ++j) if (j < w) woff += wsum[j];
    int excl = woff + v - p3;
    if (base + 0 < n) rowptr[base + 1] = excl + p0;
    if (base + 1 < n) rowptr[base + 2] = excl + p1;
    if (base + 2 < n) rowptr[base + 3] = excl + p2;
    if (base + 3 < n) rowptr[base + 4] = excl + p3;
    if (tid == 255) partials[b] = excl + p3;
    if (b == 0 && tid == 0) rowptr[0] = 0;
}

__global__ void scan2_kernel(int* __restrict__ partials, int nb) {
    int lane = threadIdx.x;
    int v = (lane < nb) ? partials[lane] : 0;
    #pragma unroll
    for (int off = 1; off < 64; off <<= 1) {
        int t = __shfl_up(v, off);
        if (lane >= off) v += t;
    }
    if (lane < nb) partials[lane] = v;  // inclusive
}

// Fused: finalize rowptr (add block offset) AND per-block degree histogram (descending).
__global__ __launch_bounds__(256) void scan3_hist_kernel(
    int* __restrict__ rowptr, int n, const int* __restrict__ partials,
    int B, int* __restrict__ bhist)
{
    __shared__ int h[256];
    __shared__ int oldv[SORT_NPB];
    int b = blockIdx.x, tid = threadIdx.x;
    h[tid] = 0;
    int off = (b == 0) ? 0 : partials[b - 1];
    #pragma unroll
    for (int j = 0; j < SORT_NPB / 256; ++j) {
        int loc = j * 256 + tid;
        int i = b * SORT_NPB + loc;
        oldv[loc] = (i < n) ? rowptr[i + 1] : 0;
    }
    __syncthreads();
    #pragma unroll
    for (int j = 0; j < SORT_NPB / 256; ++j) {
        int loc = j * 256 + tid;
        int i = b * SORT_NPB + loc;
        if (i < n) {
            int d = (loc == 0) ? oldv[0] : (oldv[loc] - oldv[loc - 1]);
            if (d > 255) d = 255;
            atomicAdd(&h[255 - d], 1);        // descending
            rowptr[i + 1] = oldv[loc] + off;  // finalize
        }
    }
    __syncthreads();
    bhist[tid * B + b] = h[tid];
}

__global__ void scatter_kernel(const int* __restrict__ src, const int* __restrict__ dst, int E,
                               const int* __restrict__ rowptr, int* __restrict__ cursor,
                               int* __restrict__ csrsrc) {
    int e = blockIdx.x * blockDim.x + threadIdx.x;
    if (e < E) {
        int d = dst[e];
        int p = atomicAdd(&cursor[d], 1);
        csrsrc[rowptr[d] + p] = src[e];
    }
}

__global__ __launch_bounds__(256) void bin_colscan_kernel(
    int* __restrict__ bhist, int B, int* __restrict__ binoff)
{
    int d = threadIdx.x;
    int run = 0;
    for (int b = 0; b < B; ++b) {
        int c = bhist[d * B + b];
        bhist[d * B + b] = run;
        run += c;
    }
    __shared__ int sd[256];
    sd[d] = run;
    __syncthreads();
    int v = run;
    for (int s = 1; s < 256; s <<= 1) {
        int t = (d >= s) ? sd[d - s] : 0;
        __syncthreads();
        sd[d] += t;
        __syncthreads();
    }
    binoff[d] = sd[d] - v;  // exclusive
}

__global__ __launch_bounds__(256) void bin_order_kernel(
    const int* __restrict__ rowptr, int n, int B,
    const int* __restrict__ bhist, const int* __restrict__ binoff,
    int* __restrict__ order)
{
    __shared__ int cur[256];
    int b = blockIdx.x, tid = threadIdx.x;
    cur[tid] = binoff[tid] + bhist[tid * B + b];
    __syncthreads();
    #pragma unroll
    for (int j = 0; j < SORT_NPB / 256; ++j) {
        int i = b * SORT_NPB + j * 256 + tid;
        if (i < n) {
            int d = rowptr[i + 1] - rowptr[i];
            if (d > 255) d = 255;
            int pos = atomicAdd(&cur[255 - d], 1);
            order[pos] = i;
        }
    }
}

// ---------------- LDS-free direct-register MFMA GEMM, ct-pairs, inline BN,
// LDS-transposed coalesced epilogue ----------------

__global__ __launch_bounds__(256, 2) void gemm_qkvs_kernel(
    const unsigned short* __restrict__ A,
    const float* __restrict__ stats, const float* __restrict__ g,
    const float* __restrict__ bb, int mode, int M,
    const unsigned short* __restrict__ Wt,
    const float* __restrict__ b0, const float* __restrict__ b1,
    const float* __restrict__ b2, const float* __restrict__ b3,
    unsigned short* __restrict__ q, unsigned short* __restrict__ kv,
    unsigned short* __restrict__ s)
{
    __shared__ float scale[128], shift[128];
    __shared__ unsigned short tile[128 * TP];
    int r0 = blockIdx.x * 128;
    int tid = threadIdx.x;
    int wid = tid >> 6, lane = tid & 63;
    int wm = wid >> 1, wn = wid & 1;
    int lr = lane & 15, lk = lane >> 4;

    if (mode && tid < 128) {
        float ssum = 0.f, qsum = 0.f;
        #pragma unroll
        for (int r = 0; r < NREP; ++r) {
            ssum += stats[r * 1024 + tid];
            qsum += stats[r * 1024 + 512 + tid];
        }
        float invN = 1.0f / (float)M;
        float mu = ssum * invN;
        float var = qsum * invN - mu * mu;
        float sc = rsqrtf(var + BN_EPS) * g[tid];
        scale[tid] = sc;
        shift[tid] = bb[tid] - mu * sc;
    }
    __syncthreads();

    bf16x8 a[4][4];
    #pragma unroll
    for (int ks = 0; ks < 4; ++ks) {
        int ko = ks * 32 + lk * 8;
        #pragma unroll
        for (int mi = 0; mi < 4; ++mi) {
            int arow = r0 + wm * 64 + mi * 16 + lr;
            int4 t = {0, 0, 0, 0};
            if (arow < M) t = *(const int4*)(A + (size_t)arow * 128 + ko);
            if (mode) {
                float4 sc0 = *(const float4*)&scale[ko];
                float4 sc1 = *(const float4*)&scale[ko + 4];
                float4 sh0 = *(const float4*)&shift[ko];
                float4 sh1 = *(const float4*)&shift[ko + 4];
                float v0 = fmaxf(bfl(t.x) * sc0.x + sh0.x, 0.f);
                float v1 = fmaxf(bfh(t.x) * sc0.y + sh0.y, 0.f);
                float v2 = fmaxf(bfl(t.y) * sc0.z + sh0.z, 0.f);
                float v3 = fmaxf(bfh(t.y) * sc0.w + sh0.w, 0.f);
                float v4 = fmaxf(bfl(t.z) * sc1.x + sh1.x, 0.f);
                float v5 = fmaxf(bfh(t.z) * sc1.y + sh1.y, 0.f);
                float v6 = fmaxf(bfl(t.w) * sc1.z + sh1.z, 0.f);
                float v7 = fmaxf(bfh(t.w) * sc1.w + sh1.w, 0.f);
                t.x = (int)packbf(v0, v1); t.y = (int)packbf(v2, v3);
                t.z = (int)packbf(v4, v5); t.w = (int)packbf(v6, v7);
            }
            a[mi][ks] = __builtin_bit_cast(bf16x8, t);
        }
    }

    #pragma unroll
    for (int cc = 0; cc < 2; ++cc) {
        int ct = blockIdx.y * 2 + cc;
        const unsigned short* W = Wt + (size_t)ct * 16384;

        f32x4 acc[4][4] = {};
        #pragma unroll
        for (int ks = 0; ks < 4; ++ks) {
            int ko = ks * 32 + lk * 8;
            bf16x8 b[4];
            #pragma unroll
            for (int nj = 0; nj < 4; ++nj) {
                int4 t = *(const int4*)(W + (size_t)(wn * 64 + nj * 16 + lr) * 128 + ko);
                b[nj] = __builtin_bit_cast(bf16x8, t);
            }
            #pragma unroll
            for (int mi = 0; mi < 4; ++mi)
                #pragma unroll
                for (int nj = 0; nj < 4; ++nj)
                    acc[mi][nj] = __builtin_amdgcn_mfma_f32_16x16x32_bf16(
                        a[mi][ks], b[nj], acc[mi][nj], 0, 0, 0);
        }

        const float* bias = (ct == 0) ? b0 : (ct == 1) ? b1 : (ct == 2) ? b2 : b3;
        __syncthreads();
        #pragma unroll
        for (int mi = 0; mi < 4; ++mi) {
            #pragma unroll
            for (int nj = 0; nj < 4; ++nj) {
                int col = wn * 64 + nj * 16 + lr;
                float bv = bias[col];
                #pragma unroll
                for (int reg = 0; reg < 4; ++reg) {
                    int rloc = wm * 64 + mi * 16 + lk * 4 + reg;
                    tile[rloc * TP + col] = f2bf(acc[mi][nj][reg] + bv);
                }
            }
        }
        __syncthreads();
        #pragma unroll
        for (int it = 0; it < 8; ++it) {
            int flat = (it * 256 + tid) * 8;
            int row = flat >> 7, col = flat & 127;
            int rw = r0 + row;
            if (rw < M) {
                int4 v = *(const int4*)&tile[row * TP + col];
                if (ct == 0) *(int4*)(q + (size_t)rw * 128 + col) = v;
                else if (ct == 1) *(int4*)(kv + (size_t)rw * 256 + col) = v;
                else if (ct == 2) *(int4*)(kv + (size_t)rw * 256 + 128 + col) = v;
                else *(int4*)(s + (size_t)rw * 128 + col) = v;
            }
        }
    }
}

// Final: out[M x 64] = BNrelu(A) @ Wo + bo (f32), inline BN; accumulates output stats.
__global__ __launch_bounds__(256, 2) void gemm_final_kernel(
    const unsigned short* __restrict__ A,
    const float* __restrict__ stats, const float* __restrict__ g,
    const float* __restrict__ bb, int M,
    const unsigned short* __restrict__ Wot, const float* __restrict__ bias,
    float* __restrict__ out, float* __restrict__ statsOut)
{
    __shared__ float scale[128], shift[128];
    __shared__ float fs[64], fq[64];
    int r0 = blockIdx.x * 128;
    int tid = threadIdx.x;
    int wid = tid >> 6, lane = tid & 63;
    int wm = wid >> 1, wn = wid & 1;
    int lr = lane & 15, lk = lane >> 4;

    if (tid < 128) {
        float ssum = 0.f, qsum = 0.f;
        #pragma unroll
        for (int r = 0; r < NREP; ++r) {
            ssum += stats[r * 1024 + tid];
            qsum += stats[r * 1024 + 512 + tid];
        }
        float invN = 1.0f / (float)M;
        float mu = ssum * invN;
        float var = qsum * invN - mu * mu;
        float sc = rsqrtf(var + BN_EPS) * g[tid];
        scale[tid] = sc;
        shift[tid] = bb[tid] - mu * sc;
    }
    if (tid < 64) { fs[tid] = 0.f; fq[tid] = 0.f; }
    __syncthreads();

    bf16x8 a[4][4];
    #pragma unroll
    for (int ks = 0; ks < 4; ++ks) {
        int ko = ks * 32 + lk * 8;
        #pragma unroll
        for (int mi = 0; mi < 4; ++mi) {
            int arow = r0 + wm * 64 + mi * 16 + lr;
            int4 t = {0, 0, 0, 0};
            if (arow < M) t = *(const int4*)(A + (size_t)arow * 128 + ko);
            float4 sc0 = *(const float4*)&scale[ko];
            float4 sc1 = *(const float4*)&scale[ko + 4];
            float4 sh0 = *(const float4*)&shift[ko];
            float4 sh1 = *(const float4*)&shift[ko + 4];
            float v0 = fmaxf(bfl(t.x) * sc0.x + sh0.x, 0.f);
            float v1 = fmaxf(bfh(t.x) * sc0.y + sh0.y, 0.f);
            float v2 = fmaxf(bfl(t.y) * sc0.z + sh0.z, 0.f);
            float v3 = fmaxf(bfh(t.y) * sc0.w + sh0.w, 0.f);
            float v4 = fmaxf(bfl(t.z) * sc1.x + sh1.x, 0.f);
            float v5 = fmaxf(bfh(t.z) * sc1.y + sh1.y, 0.f);
            float v6 = fmaxf(bfl(t.w) * sc1.z + sh1.z, 0.f);
            float v7 = fmaxf(bfh(t.w) * sc1.w + sh1.w, 0.f);
            t.x = (int)packbf(v0, v1); t.y = (int)packbf(v2, v3);
            t.z = (int)packbf(v4, v5); t.w = (int)packbf(v6, v7);
            a[mi][ks] = __builtin_bit_cast(bf16x8, t);
        }
    }

    f32x4 acc[4][2] = {};
    #pragma unroll
    for (int ks = 0; ks < 4; ++ks) {
        int ko = ks * 32 + lk * 8;
        bf16x8 b[2];
        #pragma unroll
        for (int nj = 0; nj < 2; ++nj) {
            int4 t = *(const int4*)(Wot + (size_t)(wn * 32 + nj * 16 + lr) * 128 + ko);
            b[nj] = __builtin_bit_cast(bf16x8, t);
        }
        #pragma unroll
        for (int mi = 0; mi < 4; ++mi)
            #pragma unroll
            for (int nj = 0; nj < 2; ++nj)
                acc[mi][nj] = __builtin_amdgcn_mfma_f32_16x16x32_bf16(
                    a[mi][ks], b[nj], acc[mi][nj], 0, 0, 0);
    }

    float csum[2] = {0.f, 0.f}, csq[2] = {0.f, 0.f};
    #pragma unroll
    for (int mi = 0; mi < 4; ++mi) {
        #pragma unroll
        for (int nj = 0; nj < 2; ++nj) {
            int col = wn * 32 + nj * 16 + lr;
            float bv = bias[col];
            #pragma unroll
            for (int reg = 0; reg < 4; ++reg) {
                int rw = r0 + wm * 64 + mi * 16 + lk * 4 + reg;
                if (rw < M) {
                    float val = acc[mi][nj][reg] + bv;
                    out[(size_t)rw * 64 + col] = val;
                    csum[nj] += val;
                    csq[nj] += val * val;
                }
            }
        }
    }
    #pragma unroll
    for (int nj = 0; nj < 2; ++nj) {
        csum[nj] += __shfl_xor(csum[nj], 16);
        csum[nj] += __shfl_xor(csum[nj], 32);
        csq[nj]  += __shfl_xor(csq[nj], 16);
        csq[nj]  += __shfl_xor(csq[nj], 32);
    }
    if (lane < 16) {
        #pragma unroll
        for (int nj = 0; nj < 2; ++nj) {
            int col = wn * 32 + nj * 16 + lr;
            atomicAdd(&fs[col], csum[nj]);
            atomicAdd(&fq[col], csq[nj]);
        }
    }
    __syncthreads();
    if (tid < 64) atomicAdd(&statsOut[tid], fs[tid]);
    else if (tid < 128) atomicAdd(&statsOut[512 + tid - 64], fq[tid - 64]);
}

// ---------------- Fused attention: 4 nodes/wave, unroll 8, bf16 out + replicated BN stats ----------------

__global__ __launch_bounds__(256) void attn_kernel(
    const unsigned short* __restrict__ q, const unsigned short* __restrict__ kv,
    const unsigned short* __restrict__ sk,
    const int* __restrict__ rowptr, const int* __restrict__ csrsrc,
    const int* __restrict__ order,
    unsigned short* __restrict__ hnext, float* __restrict__ stats, int N)
{
    __shared__ float ls[128], lq2[128];
    int tid = threadIdx.x;
    if (tid < 128) { ls[tid] = 0.f; lq2[tid] = 0.f; }
    __syncthreads();

    int wave = (blockIdx.x * blockDim.x + tid) >> 6;
    int lane = tid & 63;
    int gl = lane & 15;
    int slot = wave * 4 + (lane >> 4);
    bool nv = slot < N;
    int n = nv ? order[slot] : 0;

    int r0 = rowptr[n], r1 = rowptr[n + 1];
    int deg = nv ? (r1 - r0) : 0;
    int dmax = deg;
    dmax = max(dmax, __shfl_xor(dmax, 16));
    dmax = max(dmax, __shfl_xor(dmax, 32));

    int4 qu = *(const int4*)(q + (size_t)n * 128 + gl * 8);
    float qf[8];
    qf[0] = bfl(qu.x); qf[1] = bfh(qu.x); qf[2] = bfl(qu.y); qf[3] = bfh(qu.y);
    qf[4] = bfl(qu.z); qf[5] = bfh(qu.z); qf[6] = bfl(qu.w); qf[7] = bfh(qu.w);

    float m = -INFINITY, ssum = 0.f;
    float acc[8] = {};

    for (int i = 0; i < dmax; i += 8) {
        int eidx[8];
        bool av[8];
        #pragma unroll
        for (int j = 0; j < 8; ++j) {
            av[j] = (i + j) < deg;
            int e = csrsrc[r0 + i + j];   // csrsrc padded; OOB masked below
            eidx[j] = av[j] ? e : 0;
        }
        int4 K[8], V[8];
        #pragma unroll
        for (int j = 0; j < 8; ++j) {
            const unsigned short* row = kv + (size_t)eidx[j] * 256 + gl * 8;
            K[j] = *(const int4*)(row);
            V[j] = *(const int4*)(row + 128);
        }
        float sc[8];
        #pragma unroll
        for (int j = 0; j < 8; ++j) {
            float p = qf[0] * bfl(K[j].x) + qf[1] * bfh(K[j].x)
                    + qf[2] * bfl(K[j].y) + qf[3] * bfh(K[j].y)
                    + qf[4] * bfl(K[j].z) + qf[5] * bfh(K[j].z)
                    + qf[6] * bfl(K[j].w) + qf[7] * bfh(K[j].w);
            p += __shfl_xor(p, 1);
            p += __shfl_xor(p, 2);
            sc[j] = av[j] ? p * INV_SQRT_C : -INFINITY;
        }
        float mn = m;
        #pragma unroll
        for (int j = 0; j < 8; ++j) mn = fmaxf(mn, sc[j]);
        if (mn > m) {
            float scale = __expf(m - mn);
            ssum *= scale;
            #pragma unroll
            for (int c = 0; c < 8; ++c) acc[c] *= scale;
            m = mn;
        }
        #pragma unroll
        for (int j = 0; j < 8; ++j) {
            float ej = av[j] ? __expf(sc[j] - m) : 0.f;
            ssum += ej;
            acc[0] += ej * bfl(V[j].x); acc[1] += ej * bfh(V[j].x);
            acc[2] += ej * bfl(V[j].y); acc[3] += ej * bfh(V[j].y);
            acc[4] += ej * bfl(V[j].z); acc[5] += ej * bfh(V[j].z);
            acc[6] += ej * bfl(V[j].w); acc[7] += ej * bfh(V[j].w);
        }
    }

    float o[8];
    if (nv) {
        float inv = (ssum > 0.f) ? 1.0f / ssum : 0.f;
        int4 su = *(const int4*)(sk + (size_t)n * 128 + gl * 8);
        o[0] = acc[0] * inv + bfl(su.x); o[1] = acc[1] * inv + bfh(su.x);
        o[2] = acc[2] * inv + bfl(su.y); o[3] = acc[3] * inv + bfh(su.y);
        o[4] = acc[4] * inv + bfl(su.z); o[5] = acc[5] * inv + bfh(su.z);
        o[6] = acc[6] * inv + bfl(su.w); o[7] = acc[7] * inv + bfh(su.w);
        int4 st;
        st.x = (int)packbf(o[0], o[1]); st.y = (int)packbf(o[2], o[3]);
        st.z = (int)packbf(o[4], o[5]); st.w = (int)packbf(o[6], o[7]);
        *(int4*)(hnext + (size_t)n * 128 + gl * 8) = st;
    } else {
        #pragma unroll
        for (int c = 0; c < 8; ++c) o[c] = 0.f;
    }

    // fused BN stats: wave reduce -> LDS -> one replica of global stats
    float s8[8], q8[8];
    #pragma unroll
    for (int c = 0; c < 8; ++c) { s8[c] = o[c]; q8[c] = o[c] * o[c]; }
    #pragma unroll
    for (int c = 0; c < 8; ++c) {
        s8[c] += __shfl_xor(s8[c], 16); s8[c] += __shfl_xor(s8[c], 32);
        q8[c] += __shfl_xor(q8[c], 16); q8[c] += __shfl_xor(q8[c], 32);
    }
    if (lane < 16) {
        #pragma unroll
        for (int c = 0; c < 8; ++c) {
            atomicAdd(&ls[gl * 8 + c], s8[c]);
            atomicAdd(&lq2[gl * 8 + c], q8[c]);
        }
    }
    __syncthreads();
    float* srep = stats + (blockIdx.x & (NREP - 1)) * 1024;
    if (tid < 128) atomicAdd(&srep[tid], ls[tid]);
    else atomicAdd(&srep[512 + tid - 128], lq2[tid - 128]);
}

// ---------------- final BN apply ----------------

__global__ __launch_bounds__(256) void bn_apply_f32_kernel(
    const float* __restrict__ x, float* __restrict__ y,
    const float* __restrict__ stats, const float* __restrict__ g,
    const float* __restrict__ b, int N, int F)
{
    __shared__ float scale[128], shift[128];
    int tid = threadIdx.x;
    if (tid < F) {
        float invN = 1.0f / (float)N;
        float mu = stats[tid] * invN;
        float var = stats[512 + tid] * invN - mu * mu;
        float sc = rsqrtf(var + BN_EPS) * g[tid];
        scale[tid] = sc;
        shift[tid] = b[tid] - mu * sc;
    }
    __syncthreads();
    size_t total4 = (size_t)N * F >> 2;
    int Fm = F - 1;
    for (size_t t = (size_t)blockIdx.x * blockDim.x + tid; t < total4;
         t += (size_t)gridDim.x * blockDim.x) {
        size_t i = t * 4;
        int f = (int)(i & (size_t)Fm);
        float4 v = *(const float4*)(x + i);
        float4 o;
        o.x = fmaxf(v.x * scale[f + 0] + shift[f + 0], 0.f);
        o.y = fmaxf(v.y * scale[f + 1] + shift[f + 1], 0.f);
        o.z = fmaxf(v.z * scale[f + 2] + shift[f + 2], 0.f);
        o.w = fmaxf(v.w * scale[f + 3] + shift[f + 3], 0.f);
        *(float4*)(y + i) = o;
    }
}

// ---------------- launch ----------------

static inline size_t al16(size_t x) { return (x + 15) & ~(size_t)15; }

extern "C" void kernel_launch(void* const* d_in, const int* in_sizes, int n_in,
                              void* d_out, int out_size, void* d_ws, size_t ws_size,
                              hipStream_t stream) {
    const float* x    = (const float*)d_in[0];
    const int*   edge = (const int*)d_in[1];
    const float* Wq   = (const float*)d_in[2];
    const float* bq   = (const float*)d_in[3];
    const float* Wk   = (const float*)d_in[4];
    const float* bk   = (const float*)d_in[5];
    const float* Wv   = (const float*)d_in[6];
    const float* bv   = (const float*)d_in[7];
    const float* Wsk  = (const float*)d_in[8];
    const float* bsk  = (const float*)d_in[9];
    const float* bng  = (const float*)d_in[10];
    const float* bnb  = (const float*)d_in[11];
    const float* Wo   = (const float*)d_in[12];
    const float* bo   = (const float*)d_in[13];
    const float* bnog = (const float*)d_in[14];
    const float* bnob = (const float*)d_in[15];

    const int N = in_sizes[0] / D_FEAT;
    const int E = in_sizes[1] / 2;
    const int* esrc = edge;
    const int* edst = edge + E;

    const int SB = (N + SORT_NPB - 1) / SORT_NPB;
    const size_t STATS_F = (size_t)(NLAYER * NREP + 1) * 1024;

    char* wsb = (char*)d_ws;
    unsigned short* xb = (unsigned short*)wsb; wsb += al16((size_t)N * 128 * 2);
    unsigned short* kv = (unsigned short*)wsb; wsb += al16((size_t)N * 256 * 2);
    unsigned short* q  = (unsigned short*)wsb; wsb += al16((size_t)N * 128 * 2);
    unsigned short* s  = (unsigned short*)wsb; wsb += al16((size_t)N * 128 * 2);
    unsigned short* hnext = (unsigned short*)wsb; wsb += al16((size_t)N * 128 * 2);
    float* outpre = (float*)wsb; wsb += al16((size_t)N * 64 * 4);
    unsigned short* Wt  = (unsigned short*)wsb; wsb += al16((size_t)NLAYER * 4 * 16384 * 2);
    unsigned short* Wot = (unsigned short*)wsb; wsb += al16((size_t)64 * 128 * 2);
    // zero-region: stats | deg | cursor (one memset)
    float* stats  = (float*)wsb; wsb += al16(STATS_F * 4);
    int* deg      = (int*)wsb;   wsb += al16((size_t)N * 4);
    int* cursor   = (int*)wsb;   wsb += al16((size_t)N * 4);
    size_t zero_bytes = (char*)wsb - (char*)stats;
    int* rowptr   = (int*)wsb;   wsb += al16((size_t)(N + 1) * 4);
    int* csrsrc   = (int*)wsb;   wsb += al16((size_t)(E + 64) * 4);  // +pad for unroll-8 overread
    int* partials = (int*)wsb;   wsb += al16(256 * 4);
    int* bhist    = (int*)wsb;   wsb += al16((size_t)256 * SB * 4);
    int* binoff   = (int*)wsb;   wsb += al16(256 * 4);
    int* order    = (int*)wsb;   wsb += al16((size_t)N * 4);

    hipMemsetAsync(stats, 0, zero_bytes, stream);
    const int prep_blocks = 2048 + (E + 255) / 256;
    prep_kernel<<<prep_blocks, 256, 0, stream>>>(x, xb, (size_t)N * 128 / 4,
                                                 Wq, Wk, Wv, Wsk, Wo, Wt, Wot,
                                                 edst, E, deg);

    // CSR build + degree sort
    const int nb1 = (N + 1023) / 1024;
    scan1_kernel<<<nb1, 256, 0, stream>>>(deg, N, rowptr, partials);
    scan2_kernel<<<1, 64, 0, stream>>>(partials, nb1);
    scan3_hist_kernel<<<SB, 256, 0, stream>>>(rowptr, N, partials, SB, bhist);
    scatter_kernel<<<(E + 255) / 256, 256, 0, stream>>>(esrc, edst, E, rowptr, cursor, csrsrc);
    bin_colscan_kernel<<<1, 256, 0, stream>>>(bhist, SB, binoff);
    bin_order_kernel<<<SB, 256, 0, stream>>>(rowptr, N, SB, bhist, binoff, order);

    const int gemm_rb = (N + 127) / 128;
    const int attn_blocks = (N + 15) / 16;
    const unsigned short* hin = xb;
    for (int l = 0; l < NLAYER; ++l) {
        const float* statsIn = (l == 0) ? (const float*)nullptr
                                        : stats + (size_t)(l - 1) * NREP * 1024;
        const float* gIn = (l == 0) ? (const float*)nullptr : bng + (l - 1) * 128;
        const float* bIn = (l == 0) ? (const float*)nullptr : bnb + (l - 1) * 128;
        gemm_qkvs_kernel<<<dim3(gemm_rb, 2), 256, 0, stream>>>(
            hin, statsIn, gIn, bIn, (l == 0) ? 0 : 1, N,
            Wt + (size_t)l * 4 * 16384,
            bq + l * 128, bk + l * 128, bv + l * 128, bsk + l * 128,
            q, kv, s);
        attn_kernel<<<attn_blocks, 256, 0, stream>>>(q, kv, s, rowptr, csrsrc, order,
                                                     hnext, stats + (size_t)l * NREP * 1024, N);
        hin = hnext;
    }

    float* fstats = stats + (size_t)NLAYER * NREP * 1024;
    gemm_final_kernel<<<gemm_rb, 256, 0, stream>>>(
        hnext, stats + (size_t)2 * NREP * 1024, bng + 2 * 128, bnb + 2 * 128, N,
        Wot, bo, outpre, fstats);
    bn_apply_f32_kernel<<<2048, 256, 0, stream>>>(outpre, (float*)d_out, fstats,
                                                  bnog, bnob, N, 64);
}